// Round 6
// baseline (1111.649 us; speedup 1.0000x reference)
//
#include <hip/hip_runtime.h>
#include <hip/hip_bf16.h>
#include <math.h>

typedef __hip_bfloat16 bf16;
typedef short s16x8 __attribute__((ext_vector_type(8)));
typedef float f32x4 __attribute__((ext_vector_type(4)));

#define NQ 200
#define SEQ 8
#define DM 2048
#define OUTD 1152
#define LT 28
#define KDIM 4096
#define M_ALL 6300   // 700 support tuple-rows + 5600 query tuple-rows
#define M_PAD 6400   // 50 tiles of 128
#define SM 5600
#define SN_PAD 768
#define ATT_STRIDE 704   // 700 attn cols (5 classes x 140) + 4 pad
#define NPEX 1800
#define VS_STRIDE 708    // LDS stride for Vs slices

__device__ __forceinline__ float bf2f(bf16 v) { return __bfloat162float(v); }
__device__ __forceinline__ bf16 f2bf(float v) { return __float2bfloat16(v); }
__device__ __forceinline__ float bits2f(unsigned short u) {
    unsigned int i = ((unsigned int)u) << 16;
    float f; __builtin_memcpy(&f, &i, 4); return f;
}
__device__ __forceinline__ unsigned short f2bits(float f) {
    bf16 b = __float2bfloat16(f);
    unsigned short u; __builtin_memcpy(&u, &b, 2); return u;
}

__device__ const int TUP_A[LT] = {0,0,0,0,0,0,0,1,1,1,1,1,1,2,2,2,2,2,3,3,3,3,4,4,4,5,5,6};
__device__ const int TUP_B[LT] = {1,2,3,4,5,6,7,2,3,4,5,6,7,3,4,5,6,7,4,5,6,7,5,6,7,6,7,7};
__device__ const int PAIR_A[15] = {0,0,0,0,0,1,1,1,1,2,2,2,3,3,4};
__device__ const int PAIR_B[15] = {0,1,2,3,4,1,2,3,4,2,3,4,3,4,4};

// ---------------------------------------------------------------------------
// weight convert: fp32 -> bf16, vectorized (1152*4096 elements)
// ---------------------------------------------------------------------------
__global__ __launch_bounds__(256) void wconv_k(const float4* __restrict__ w,
                                               ushort4* __restrict__ o) {
    int i = blockIdx.x * 256 + threadIdx.x;   // 1,179,648 float4 groups
    float4 v = w[i];
    ushort4 r;
    r.x = f2bits(v.x); r.y = f2bits(v.y); r.z = f2bits(v.z); r.w = f2bits(v.w);
    o[i] = r;
}

// ---------------------------------------------------------------------------
// pex[r][d] = fp32 src[n][s][d] + pe[s][d], rounded to bf16.
// r<200: support (n=r/8, s=r%8); else query.
// ---------------------------------------------------------------------------
__global__ __launch_bounds__(256) void pex_k(const float* __restrict__ sup,
                                             const float* __restrict__ qry,
                                             bf16* __restrict__ pex) {
    int r = blockIdx.x, t = threadIdx.x;
    int n, s;
    const float* src;
    if (r < 200) { n = r >> 3; s = r & 7; src = sup; }
    else { int rr = r - 200; n = rr >> 3; s = rr & 7; src = qry; }
    const float* row = src + ((size_t)n * SEQ + s) * DM;
    bf16* orow = pex + (size_t)r * DM;
    for (int d = t; d < DM; d += 256) {
        float dv = expf((float)(d & ~1) * (-9.210340371976184f / 2048.0f));
        float ang = (float)s * dv;
        float pe = (d & 1) ? cosf(ang) * 0.1f : sinf(ang) * 0.1f;
        orow[d] = f2bf(row[d] + pe);
    }
}

// ---------------------------------------------------------------------------
// Projection GEMM, A gathered from pex via tuple indirection, B = bf16 W,
// bias fp32. C[m][n] = sum_k pexrow(m, k>>11)[k&2047]*W[n][k] + bias[n].
// 128x128 tile, 4 waves, 4x4 mfma_f32_16x16x32_bf16; LDS k-quad-major.
// ---------------------------------------------------------------------------
__global__ __launch_bounds__(256) void gemm_projx(
    const unsigned short* __restrict__ pex,
    const unsigned short* __restrict__ W, const float* __restrict__ bias,
    bf16* __restrict__ C) {
    const int tile_m = blockIdx.x * 128, tile_n = blockIdx.y * 128;
    __shared__ unsigned short As[4 * 128 * 8];
    __shared__ unsigned short Bs[4 * 128 * 8];
    const int t = threadIdx.x, lane = t & 63, wave = t >> 6;
    const int wm = (wave & 1) * 64, wn = (wave >> 1) * 64;
    const int srow = t >> 1, sq0 = (t & 1) * 2;
    const int m = tile_m + srow;
    const bool valid = m < M_ALL;
    const unsigned short* row0 = pex;
    const unsigned short* row1 = pex;
    if (valid) {
        int mm = m < 700 ? m : m - 700;
        int base = m < 700 ? 0 : 200;
        int n = mm / LT, l = mm - n * LT;
        row0 = pex + (size_t)(base + n * 8 + TUP_A[l]) * DM + (t & 1) * 16;
        row1 = pex + (size_t)(base + n * 8 + TUP_B[l]) * DM + (t & 1) * 16;
    }
    const unsigned short* Wg = W + (size_t)(tile_n + srow) * KDIM + (t & 1) * 16;
    unsigned short* AsW0 = &As[((sq0 + 0) * 128 + srow) * 8];
    unsigned short* AsW1 = &As[((sq0 + 1) * 128 + srow) * 8];
    unsigned short* BsW0 = &Bs[((sq0 + 0) * 128 + srow) * 8];
    unsigned short* BsW1 = &Bs[((sq0 + 1) * 128 + srow) * 8];
    const int fr = lane & 15, quad = lane >> 4;

    f32x4 acc[4][4];
#pragma unroll
    for (int i = 0; i < 4; i++)
#pragma unroll
        for (int j = 0; j < 4; j++) acc[i][j] = {0.f, 0.f, 0.f, 0.f};

    for (int k0 = 0; k0 < KDIM; k0 += 32) {
        const unsigned short* rp = (k0 & 2048) ? row1 : row0;
        const int d0 = k0 & 2047;
        uint4 a0 = {0, 0, 0, 0}, a1 = {0, 0, 0, 0};
        if (valid) {
            a0 = *(const uint4*)(rp + d0);
            a1 = *(const uint4*)(rp + d0 + 8);
        }
        uint4 b0 = *(const uint4*)(Wg + k0);
        uint4 b1 = *(const uint4*)(Wg + k0 + 8);
        __syncthreads();
        *(uint4*)AsW0 = a0; *(uint4*)AsW1 = a1;
        *(uint4*)BsW0 = b0; *(uint4*)BsW1 = b1;
        __syncthreads();
        s16x8 af[4], bfv[4];
#pragma unroll
        for (int i = 0; i < 4; i++)
            af[i] = *(const s16x8*)&As[(quad * 128 + wm + i * 16 + fr) * 8];
#pragma unroll
        for (int j = 0; j < 4; j++)
            bfv[j] = *(const s16x8*)&Bs[(quad * 128 + wn + j * 16 + fr) * 8];
#pragma unroll
        for (int i = 0; i < 4; i++)
#pragma unroll
            for (int j = 0; j < 4; j++)
                acc[i][j] = __builtin_amdgcn_mfma_f32_16x16x32_bf16(af[i], bfv[j], acc[i][j], 0, 0, 0);
    }

    const int rb = quad * 4;
#pragma unroll
    for (int i = 0; i < 4; i++)
#pragma unroll
        for (int j = 0; j < 4; j++) {
            const int col = tile_n + wn + j * 16 + fr;
            float bv = bias[col];
#pragma unroll
            for (int r = 0; r < 4; r++) {
                const int row = tile_m + wm + i * 16 + rb + r;
                C[(size_t)row * OUTD + col] = f2bf(acc[i][j][r] + bv);
            }
        }
}

// ---------------------------------------------------------------------------
// LayerNorm in place (bf16); rows >= M_ALL -> zeros (scores pad operand)
// ---------------------------------------------------------------------------
__global__ __launch_bounds__(256) void ln_k(bf16* __restrict__ ks,
                                            const float* __restrict__ gg,
                                            const float* __restrict__ bb) {
    int row = blockIdx.x, t = threadIdx.x, lane = t & 63, wave = t >> 6;
    if (row >= M_ALL) {
        for (int c = t; c < OUTD; c += 256) ks[(size_t)row * OUTD + c] = f2bf(0.f);
        return;
    }
    bf16* xr = ks + (size_t)row * OUTD;
    float vals[5];
    int cnt = 0;
    float s = 0.f, s2 = 0.f;
    for (int c = t; c < OUTD; c += 256) {
        float v = bf2f(xr[c]);
        vals[cnt++] = v;
        s += v; s2 += v * v;
    }
    for (int o = 32; o > 0; o >>= 1) { s += __shfl_xor(s, o); s2 += __shfl_xor(s2, o); }
    __shared__ float r1[4], r2[4];
    if (lane == 0) { r1[wave] = s; r2[wave] = s2; }
    __syncthreads();
    s = r1[0] + r1[1] + r1[2] + r1[3];
    s2 = r2[0] + r2[1] + r2[2] + r2[3];
    float mu = s * (1.f / OUTD);
    float var = s2 * (1.f / OUTD) - mu * mu;
    float inv = rsqrtf(fmaxf(var, 0.f) + 1e-5f);
    cnt = 0;
    for (int c = t; c < OUTD; c += 256)
        xr[c] = f2bf((vals[cnt++] - mu) * inv * gg[c] + bb[c]);
}

// ---------------------------------------------------------------------------
// scores GEMM: sc[5632][768] bf16 = (ksq @ kss^T) / sqrt(1152)
// ---------------------------------------------------------------------------
__global__ __launch_bounds__(256) void gemm_scores(
    const unsigned short* __restrict__ A,   // ks + 700*OUTD
    const unsigned short* __restrict__ B,   // ks
    bf16* __restrict__ C) {
    const int tile_m = blockIdx.x * 128, tile_n = blockIdx.y * 128;
    __shared__ unsigned short As[4 * 128 * 8];
    __shared__ unsigned short Bs[4 * 128 * 8];
    const int t = threadIdx.x, lane = t & 63, wave = t >> 6;
    const int wm = (wave & 1) * 64, wn = (wave >> 1) * 64;
    const int srow = t >> 1, sq0 = (t & 1) * 2;
    const unsigned short* Ag = A + (size_t)(tile_m + srow) * OUTD + (t & 1) * 16;
    const unsigned short* Bg = B + (size_t)(tile_n + srow) * OUTD + (t & 1) * 16;
    unsigned short* AsW0 = &As[((sq0 + 0) * 128 + srow) * 8];
    unsigned short* AsW1 = &As[((sq0 + 1) * 128 + srow) * 8];
    unsigned short* BsW0 = &Bs[((sq0 + 0) * 128 + srow) * 8];
    unsigned short* BsW1 = &Bs[((sq0 + 1) * 128 + srow) * 8];
    const int fr = lane & 15, quad = lane >> 4;

    f32x4 acc[4][4];
#pragma unroll
    for (int i = 0; i < 4; i++)
#pragma unroll
        for (int j = 0; j < 4; j++) acc[i][j] = {0.f, 0.f, 0.f, 0.f};

    for (int k0 = 0; k0 < OUTD; k0 += 32) {
        uint4 a0 = *(const uint4*)(Ag + k0);
        uint4 a1 = *(const uint4*)(Ag + k0 + 8);
        uint4 b0 = *(const uint4*)(Bg + k0);
        uint4 b1 = *(const uint4*)(Bg + k0 + 8);
        __syncthreads();
        *(uint4*)AsW0 = a0; *(uint4*)AsW1 = a1;
        *(uint4*)BsW0 = b0; *(uint4*)BsW1 = b1;
        __syncthreads();
        s16x8 af[4], bfv[4];
#pragma unroll
        for (int i = 0; i < 4; i++)
            af[i] = *(const s16x8*)&As[(quad * 128 + wm + i * 16 + fr) * 8];
#pragma unroll
        for (int j = 0; j < 4; j++)
            bfv[j] = *(const s16x8*)&Bs[(quad * 128 + wn + j * 16 + fr) * 8];
#pragma unroll
        for (int i = 0; i < 4; i++)
#pragma unroll
            for (int j = 0; j < 4; j++)
                acc[i][j] = __builtin_amdgcn_mfma_f32_16x16x32_bf16(af[i], bfv[j], acc[i][j], 0, 0, 0);
    }

    const int rb = quad * 4;
#pragma unroll
    for (int i = 0; i < 4; i++)
#pragma unroll
        for (int j = 0; j < 4; j++) {
            const int col = tile_n + wn + j * 16 + fr;
#pragma unroll
            for (int r = 0; r < 4; r++) {
                const int row = tile_m + wm + i * 16 + rb + r;
                C[(size_t)row * SN_PAD + col] = f2bf(acc[i][j][r] * 0.029462782549439484f);
            }
        }
}

// ---------------------------------------------------------------------------
// softmax over 5 blocks of 140 support cols; attn row stride 704
// ---------------------------------------------------------------------------
__global__ __launch_bounds__(256) void softmax_k(const bf16* __restrict__ sc,
                                                 bf16* __restrict__ attn) {
    int row = blockIdx.x, t = threadIdx.x, lane = t & 63, wave = t >> 6;
    __shared__ float redm[4], reds[4];
    for (int w = 0; w < 5; w++) {
        float v = (t < 140) ? bf2f(sc[(size_t)row * SN_PAD + w * 140 + t]) : -3.0e38f;
        float m = v;
        for (int o = 32; o > 0; o >>= 1) m = fmaxf(m, __shfl_xor(m, o));
        if (lane == 0) redm[wave] = m;
        __syncthreads();
        m = fmaxf(fmaxf(redm[0], redm[1]), fmaxf(redm[2], redm[3]));
        float e = (t < 140) ? __expf(v - m) : 0.f;
        float s = e;
        for (int o = 32; o > 0; o >>= 1) s += __shfl_xor(s, o);
        if (lane == 0) reds[wave] = s;
        __syncthreads();
        s = reds[0] + reds[1] + reds[2] + reds[3];
        if (t < 140) attn[(size_t)row * ATT_STRIDE + w * 140 + t] = f2bf(e / s);
        __syncthreads();
    }
}

// ---------------------------------------------------------------------------
// Fused proto + Gram reduction. Block = (d-slice of 32 dims, query q).
// ps[w][d] = sum_j attn[q,l, w*140+j] * vs[w*140+j][d]; accumulate 21 stats.
// ---------------------------------------------------------------------------
__global__ __launch_bounds__(256) void protored_k(const bf16* __restrict__ vs,
                                                  const bf16* __restrict__ attn,
                                                  float* __restrict__ gbuf) {
    const int ds = blockIdx.x;   // 0..35
    const int q  = blockIdx.y;   // 0..199
    const int t = threadIdx.x;
    const int d0 = ds * 32;
    __shared__ unsigned short Vs[32 * VS_STRIDE];
    __shared__ unsigned short arow[704];
    __shared__ float vqs[32];
    __shared__ float ps[5 * 32];

    const unsigned short* vsu = (const unsigned short*)vs;
    for (int i = t; i < 700 * 8; i += 256) {
        int col = i >> 3, d4 = (i & 7) * 4;
        ushort4 v4 = *(const ushort4*)(vsu + (size_t)col * OUTD + d0 + d4);
        Vs[(d4 + 0) * VS_STRIDE + col] = v4.x;
        Vs[(d4 + 1) * VS_STRIDE + col] = v4.y;
        Vs[(d4 + 2) * VS_STRIDE + col] = v4.z;
        Vs[(d4 + 3) * VS_STRIDE + col] = v4.w;
    }

    float r3[3] = {0.f, 0.f, 0.f};
    const int slot = t >> 5, d = t & 31;
    const unsigned short* attu = (const unsigned short*)attn;

    for (int l = 0; l < LT; l++) {
        __syncthreads();
        const size_t arbase = (size_t)(q * LT + l) * ATT_STRIDE;
        for (int i = t; i < 700; i += 256) arow[i] = attu[arbase + i];
        if (t < 32) vqs[t] = bf2f(vs[(size_t)(700 + q * LT + l) * OUTD + d0 + t]);
        __syncthreads();
        if (t < 160) {
            int w = t >> 5, dd = t & 31;
            float acc = 0.f;
            const unsigned short* vrow = &Vs[dd * VS_STRIDE + w * 140];
            const unsigned short* ar = &arow[w * 140];
#pragma unroll
            for (int j = 0; j < 140; j += 4) {
                ushort4 av = *(const ushort4*)(ar + j);
                ushort4 bv = *(const ushort4*)(vrow + j);
                acc += bits2f(av.x) * bits2f(bv.x) + bits2f(av.y) * bits2f(bv.y)
                     + bits2f(av.z) * bits2f(bv.z) + bits2f(av.w) * bits2f(bv.w);
            }
            ps[w * 32 + dd] = acc;
        }
        __syncthreads();
        float vq = vqs[d];
#pragma unroll
        for (int it = 0; it < 3; it++) {
            int qi = it * 8 + slot;
            float val = 0.f;
            if (qi < 15) val = ps[PAIR_A[qi] * 32 + d] * ps[PAIR_B[qi] * 32 + d];
            else if (qi < 20) val = vq * ps[(qi - 15) * 32 + d];
            else if (qi == 20) val = vq * vq;
            r3[it] += val;
        }
    }
#pragma unroll
    for (int it = 0; it < 3; it++) {
        float v = r3[it];
        for (int o = 16; o > 0; o >>= 1) v += __shfl_xor(v, o);
        int qi = it * 8 + slot;
        if (d == 0 && qi < 21) atomicAdd(&gbuf[q * 21 + qi], v);
    }
}

// ---------------------------------------------------------------------------
// out (fp32): per q -> 25 sim + 5 ori
// ---------------------------------------------------------------------------
__global__ __launch_bounds__(64) void out_k(const float* __restrict__ gbuf,
                                            float* __restrict__ out) {
    int q = blockIdx.x;
    if (threadIdx.x != 0) return;
    const float* r = gbuf + q * 21;
    float G[5][5];
    int c = 0;
    for (int a = 0; a < 5; a++)
        for (int b = a; b < 5; b++) { G[a][b] = r[c]; G[b][a] = r[c]; c++; }
    float e = r[20];
    float nrm[5];
    for (int a = 0; a < 5; a++) nrm[a] = sqrtf(fmaxf(G[a][a], 0.f));
    for (int a = 0; a < 5; a++)
        for (int b = 0; b < 5; b++)
            out[(size_t)q * 25 + a * 5 + b] = G[a][b] / fmaxf(nrm[a] * nrm[b], 1e-8f);
    for (int w = 0; w < 5; w++)
        out[5000 + (size_t)q * 5 + w] = -(e - 2.f * r[15 + w] + G[w][w]) * (1.f / 28.f);
}

// ---------------------------------------------------------------------------
extern "C" void kernel_launch(void* const* d_in, const int* in_sizes, int n_in,
                              void* d_out, int out_size, void* d_ws, size_t ws_size,
                              hipStream_t stream) {
    const float* sup = (const float*)d_in[0];
    // d_in[1] = support_labels int32 — unused (sorted equal-shot)
    const float* qry = (const float*)d_in[2];
    const float* k_w = (const float*)d_in[3];
    const float* k_b = (const float*)d_in[4];
    const float* v_w = (const float*)d_in[5];
    const float* v_b = (const float*)d_in[6];
    const float* lng = (const float*)d_in[7];
    const float* lnb = (const float*)d_in[8];
    (void)in_sizes; (void)n_in; (void)out_size; (void)ws_size;

    // layout (bytes), peak 46,317,984 (< verified ws_size >= 54.5 MB):
    //   w    @0          9,437,184  (k_w bf16, then v_w bf16 reuses slot)
    //   pex  @9,437,184  7,372,800
    //   ks   @16,809,984 14,745,600
    //   vs   @31,555,584 14,745,600
    //   sc   @0          8,650,752  (aliases w — dead after projections)
    //   attn @8,650,752  7,929,856  (aliases w/pex tail — both dead)
    //   gbuf @46,301,184 16,800
    char* ws = (char*)d_ws;
    bf16* wbf   = (bf16*)(ws + 0);
    bf16* pex   = (bf16*)(ws + 9437184);
    bf16* ks    = (bf16*)(ws + 16809984);
    bf16* vs    = (bf16*)(ws + 31555584);
    bf16* sc    = (bf16*)(ws + 0);
    bf16* attn  = (bf16*)(ws + 8650752);
    float* gbuf = (float*)(ws + 46301184);

    pex_k<<<dim3(NPEX), dim3(256), 0, stream>>>(sup, qry, pex);

    // K projection (convert k_w, GEMM)
    wconv_k<<<dim3(4608), dim3(256), 0, stream>>>(
        (const float4*)k_w, (ushort4*)wbf);
    gemm_projx<<<dim3(50, 9), dim3(256), 0, stream>>>(
        (const unsigned short*)pex, (const unsigned short*)wbf, k_b, ks);

    // V projection (convert v_w into same slot, GEMM)
    wconv_k<<<dim3(4608), dim3(256), 0, stream>>>(
        (const float4*)v_w, (ushort4*)wbf);
    gemm_projx<<<dim3(50, 9), dim3(256), 0, stream>>>(
        (const unsigned short*)pex, (const unsigned short*)wbf, v_b, vs);

    ln_k<<<dim3(M_PAD), dim3(256), 0, stream>>>(ks, lng, lnb);

    gemm_scores<<<dim3(44, 6), dim3(256), 0, stream>>>(
        (const unsigned short*)(ks + (size_t)700 * OUTD),
        (const unsigned short*)ks, sc);

    softmax_k<<<dim3(SM), dim3(256), 0, stream>>>(sc, attn);

    hipMemsetAsync(gbuf, 0, 200 * 21 * sizeof(float), stream);
    protored_k<<<dim3(36, NQ), dim3(256), 0, stream>>>(vs, attn, gbuf);

    out_k<<<dim3(NQ), dim3(64), 0, stream>>>(gbuf, (float*)d_out);
}

// Round 7
// 460.818 us; speedup vs baseline: 2.4123x; 2.4123x over previous
//
#include <hip/hip_runtime.h>
#include <hip/hip_bf16.h>
#include <math.h>

typedef __hip_bfloat16 bf16;
typedef short s16x8 __attribute__((ext_vector_type(8)));
typedef float f32x4 __attribute__((ext_vector_type(4)));

#define NQ 200
#define SEQ 8
#define DM 2048
#define OUTD 1152
#define LT 28
#define KDIM 4096
#define M_ALL 6300   // 700 support tuple-rows + 5600 query tuple-rows
#define M_PAD 6400   // 50 tiles of 128
#define SM 5600
#define SN_PAD 768
#define ATT_STRIDE 720   // 700 attn cols (5 x 140) + 20 pad (K=160 window safe)
#define NPEX 1800
#define KP 160           // padded proto-GEMM K (140 -> 160)
#define CH_Q 50          // queries per proto chunk
#define CH_ROWS 1400     // rows per chunk
#define CH_MPAD 1408     // 11 tiles of 128

__device__ __forceinline__ float bf2f(bf16 v) { return __bfloat162float(v); }
__device__ __forceinline__ bf16 f2bf(float v) { return __float2bfloat16(v); }
__device__ __forceinline__ unsigned short f2bits(float f) {
    bf16 b = __float2bfloat16(f);
    unsigned short u; __builtin_memcpy(&u, &b, 2); return u;
}

__device__ const int TUP_A[LT] = {0,0,0,0,0,0,0,1,1,1,1,1,1,2,2,2,2,2,3,3,3,3,4,4,4,5,5,6};
__device__ const int TUP_B[LT] = {1,2,3,4,5,6,7,2,3,4,5,6,7,3,4,5,6,7,4,5,6,7,5,6,7,6,7,7};

// ---------------------------------------------------------------------------
// weight convert: fp32 -> bf16 (1152*4096 elements)
// ---------------------------------------------------------------------------
__global__ __launch_bounds__(256) void wconv_k(const float4* __restrict__ w,
                                               ushort4* __restrict__ o) {
    int i = blockIdx.x * 256 + threadIdx.x;
    float4 v = w[i];
    ushort4 r;
    r.x = f2bits(v.x); r.y = f2bits(v.y); r.z = f2bits(v.z); r.w = f2bits(v.w);
    o[i] = r;
}

// ---------------------------------------------------------------------------
// pex[r][d] = fp32 src[n][s][d] + pe[s][d] -> bf16
// ---------------------------------------------------------------------------
__global__ __launch_bounds__(256) void pex_k(const float* __restrict__ sup,
                                             const float* __restrict__ qry,
                                             bf16* __restrict__ pex) {
    int r = blockIdx.x, t = threadIdx.x;
    int n, s;
    const float* src;
    if (r < 200) { n = r >> 3; s = r & 7; src = sup; }
    else { int rr = r - 200; n = rr >> 3; s = rr & 7; src = qry; }
    const float* row = src + ((size_t)n * SEQ + s) * DM;
    bf16* orow = pex + (size_t)r * DM;
    for (int d = t; d < DM; d += 256) {
        float dv = expf((float)(d & ~1) * (-9.210340371976184f / 2048.0f));
        float ang = (float)s * dv;
        float pe = (d & 1) ? cosf(ang) * 0.1f : sinf(ang) * 0.1f;
        orow[d] = f2bf(row[d] + pe);
    }
}

// ---------------------------------------------------------------------------
// Projection GEMM, A gathered from pex via tuple indirection, fp32 bias.
// ---------------------------------------------------------------------------
__global__ __launch_bounds__(256) void gemm_projx(
    const unsigned short* __restrict__ pex,
    const unsigned short* __restrict__ W, const float* __restrict__ bias,
    bf16* __restrict__ C) {
    const int tile_m = blockIdx.x * 128, tile_n = blockIdx.y * 128;
    __shared__ unsigned short As[4 * 128 * 8];
    __shared__ unsigned short Bs[4 * 128 * 8];
    const int t = threadIdx.x, lane = t & 63, wave = t >> 6;
    const int wm = (wave & 1) * 64, wn = (wave >> 1) * 64;
    const int srow = t >> 1, sq0 = (t & 1) * 2;
    const int m = tile_m + srow;
    const bool valid = m < M_ALL;
    const unsigned short* row0 = pex;
    const unsigned short* row1 = pex;
    if (valid) {
        int mm = m < 700 ? m : m - 700;
        int base = m < 700 ? 0 : 200;
        int n = mm / LT, l = mm - n * LT;
        row0 = pex + (size_t)(base + n * 8 + TUP_A[l]) * DM + (t & 1) * 16;
        row1 = pex + (size_t)(base + n * 8 + TUP_B[l]) * DM + (t & 1) * 16;
    }
    const unsigned short* Wg = W + (size_t)(tile_n + srow) * KDIM + (t & 1) * 16;
    unsigned short* AsW0 = &As[((sq0 + 0) * 128 + srow) * 8];
    unsigned short* AsW1 = &As[((sq0 + 1) * 128 + srow) * 8];
    unsigned short* BsW0 = &Bs[((sq0 + 0) * 128 + srow) * 8];
    unsigned short* BsW1 = &Bs[((sq0 + 1) * 128 + srow) * 8];
    const int fr = lane & 15, quad = lane >> 4;

    f32x4 acc[4][4];
#pragma unroll
    for (int i = 0; i < 4; i++)
#pragma unroll
        for (int j = 0; j < 4; j++) acc[i][j] = {0.f, 0.f, 0.f, 0.f};

    for (int k0 = 0; k0 < KDIM; k0 += 32) {
        const unsigned short* rp = (k0 & 2048) ? row1 : row0;
        const int d0 = k0 & 2047;
        uint4 a0 = {0, 0, 0, 0}, a1 = {0, 0, 0, 0};
        if (valid) {
            a0 = *(const uint4*)(rp + d0);
            a1 = *(const uint4*)(rp + d0 + 8);
        }
        uint4 b0 = *(const uint4*)(Wg + k0);
        uint4 b1 = *(const uint4*)(Wg + k0 + 8);
        __syncthreads();
        *(uint4*)AsW0 = a0; *(uint4*)AsW1 = a1;
        *(uint4*)BsW0 = b0; *(uint4*)BsW1 = b1;
        __syncthreads();
        s16x8 af[4], bfv[4];
#pragma unroll
        for (int i = 0; i < 4; i++)
            af[i] = *(const s16x8*)&As[(quad * 128 + wm + i * 16 + fr) * 8];
#pragma unroll
        for (int j = 0; j < 4; j++)
            bfv[j] = *(const s16x8*)&Bs[(quad * 128 + wn + j * 16 + fr) * 8];
#pragma unroll
        for (int i = 0; i < 4; i++)
#pragma unroll
            for (int j = 0; j < 4; j++)
                acc[i][j] = __builtin_amdgcn_mfma_f32_16x16x32_bf16(af[i], bfv[j], acc[i][j], 0, 0, 0);
    }

    const int rb = quad * 4;
#pragma unroll
    for (int i = 0; i < 4; i++)
#pragma unroll
        for (int j = 0; j < 4; j++) {
            const int col = tile_n + wn + j * 16 + fr;
            float bv = bias[col];
#pragma unroll
            for (int r = 0; r < 4; r++) {
                const int row = tile_m + wm + i * 16 + rb + r;
                C[(size_t)row * OUTD + col] = f2bf(acc[i][j][r] + bv);
            }
        }
}

// ---------------------------------------------------------------------------
// Generic MFMA bf16 GEMM: C = scale*A*B^T, z shifts A/B/C by aZ/bZ/cZ elems.
// Used for the per-class proto chunks.
// ---------------------------------------------------------------------------
__global__ __launch_bounds__(256) void gemm_bt(
    const bf16* __restrict__ A, int lda, size_t aZ,
    const bf16* __restrict__ B, int ldb, size_t bZ,
    float scale, bf16* __restrict__ C, int ldc, size_t cZ, int K) {
    const unsigned short* Ag0 = (const unsigned short*)A + aZ * blockIdx.z;
    const unsigned short* Bg0 = (const unsigned short*)B + bZ * blockIdx.z;
    const size_t cbase = cZ * blockIdx.z;
    const int tile_m = blockIdx.x * 128, tile_n = blockIdx.y * 128;
    __shared__ unsigned short As[4 * 128 * 8];
    __shared__ unsigned short Bs[4 * 128 * 8];
    const int t = threadIdx.x, lane = t & 63, wave = t >> 6;
    const int wm = (wave & 1) * 64, wn = (wave >> 1) * 64;
    const int srow = t >> 1, sq0 = (t & 1) * 2;
    const unsigned short* Ag = Ag0 + (size_t)(tile_m + srow) * lda + (t & 1) * 16;
    const unsigned short* Bg = Bg0 + (size_t)(tile_n + srow) * ldb + (t & 1) * 16;
    unsigned short* AsW0 = &As[((sq0 + 0) * 128 + srow) * 8];
    unsigned short* AsW1 = &As[((sq0 + 1) * 128 + srow) * 8];
    unsigned short* BsW0 = &Bs[((sq0 + 0) * 128 + srow) * 8];
    unsigned short* BsW1 = &Bs[((sq0 + 1) * 128 + srow) * 8];
    const int fr = lane & 15, quad = lane >> 4;

    f32x4 acc[4][4];
#pragma unroll
    for (int i = 0; i < 4; i++)
#pragma unroll
        for (int j = 0; j < 4; j++) acc[i][j] = {0.f, 0.f, 0.f, 0.f};

    for (int k0 = 0; k0 < K; k0 += 32) {
        uint4 a0 = *(const uint4*)(Ag + k0);
        uint4 a1 = *(const uint4*)(Ag + k0 + 8);
        uint4 b0 = *(const uint4*)(Bg + k0);
        uint4 b1 = *(const uint4*)(Bg + k0 + 8);
        __syncthreads();
        *(uint4*)AsW0 = a0; *(uint4*)AsW1 = a1;
        *(uint4*)BsW0 = b0; *(uint4*)BsW1 = b1;
        __syncthreads();
        s16x8 af[4], bfv[4];
#pragma unroll
        for (int i = 0; i < 4; i++)
            af[i] = *(const s16x8*)&As[(quad * 128 + wm + i * 16 + fr) * 8];
#pragma unroll
        for (int j = 0; j < 4; j++)
            bfv[j] = *(const s16x8*)&Bs[(quad * 128 + wn + j * 16 + fr) * 8];
#pragma unroll
        for (int i = 0; i < 4; i++)
#pragma unroll
            for (int j = 0; j < 4; j++)
                acc[i][j] = __builtin_amdgcn_mfma_f32_16x16x32_bf16(af[i], bfv[j], acc[i][j], 0, 0, 0);
    }

    const int rb = quad * 4;
#pragma unroll
    for (int i = 0; i < 4; i++)
#pragma unroll
        for (int j = 0; j < 4; j++) {
            const int col = tile_n + wn + j * 16 + fr;
#pragma unroll
            for (int r = 0; r < 4; r++) {
                const int row = tile_m + wm + i * 16 + rb + r;
                C[cbase + (size_t)row * ldc + col] = f2bf(acc[i][j][r] * scale);
            }
        }
}

// ---------------------------------------------------------------------------
// LayerNorm in place (bf16); rows >= M_ALL -> zeros
// ---------------------------------------------------------------------------
__global__ __launch_bounds__(256) void ln_k(bf16* __restrict__ ks,
                                            const float* __restrict__ gg,
                                            const float* __restrict__ bb) {
    int row = blockIdx.x, t = threadIdx.x, lane = t & 63, wave = t >> 6;
    if (row >= M_ALL) {
        for (int c = t; c < OUTD; c += 256) ks[(size_t)row * OUTD + c] = f2bf(0.f);
        return;
    }
    bf16* xr = ks + (size_t)row * OUTD;
    float vals[5];
    int cnt = 0;
    float s = 0.f, s2 = 0.f;
    for (int c = t; c < OUTD; c += 256) {
        float v = bf2f(xr[c]);
        vals[cnt++] = v;
        s += v; s2 += v * v;
    }
    for (int o = 32; o > 0; o >>= 1) { s += __shfl_xor(s, o); s2 += __shfl_xor(s2, o); }
    __shared__ float r1[4], r2[4];
    if (lane == 0) { r1[wave] = s; r2[wave] = s2; }
    __syncthreads();
    s = r1[0] + r1[1] + r1[2] + r1[3];
    s2 = r2[0] + r2[1] + r2[2] + r2[3];
    float mu = s * (1.f / OUTD);
    float var = s2 * (1.f / OUTD) - mu * mu;
    float inv = rsqrtf(fmaxf(var, 0.f) + 1e-5f);
    cnt = 0;
    for (int c = t; c < OUTD; c += 256)
        xr[c] = f2bf((vals[cnt++] - mu) * inv * gg[c] + bb[c]);
}

// ---------------------------------------------------------------------------
// scores GEMM: sc[5632][768] bf16 = (ksq @ kss^T) / sqrt(1152)
// ---------------------------------------------------------------------------
__global__ __launch_bounds__(256) void gemm_scores(
    const unsigned short* __restrict__ A,
    const unsigned short* __restrict__ B,
    bf16* __restrict__ C) {
    const int tile_m = blockIdx.x * 128, tile_n = blockIdx.y * 128;
    __shared__ unsigned short As[4 * 128 * 8];
    __shared__ unsigned short Bs[4 * 128 * 8];
    const int t = threadIdx.x, lane = t & 63, wave = t >> 6;
    const int wm = (wave & 1) * 64, wn = (wave >> 1) * 64;
    const int srow = t >> 1, sq0 = (t & 1) * 2;
    const unsigned short* Ag = A + (size_t)(tile_m + srow) * OUTD + (t & 1) * 16;
    const unsigned short* Bg = B + (size_t)(tile_n + srow) * OUTD + (t & 1) * 16;
    unsigned short* AsW0 = &As[((sq0 + 0) * 128 + srow) * 8];
    unsigned short* AsW1 = &As[((sq0 + 1) * 128 + srow) * 8];
    unsigned short* BsW0 = &Bs[((sq0 + 0) * 128 + srow) * 8];
    unsigned short* BsW1 = &Bs[((sq0 + 1) * 128 + srow) * 8];
    const int fr = lane & 15, quad = lane >> 4;

    f32x4 acc[4][4];
#pragma unroll
    for (int i = 0; i < 4; i++)
#pragma unroll
        for (int j = 0; j < 4; j++) acc[i][j] = {0.f, 0.f, 0.f, 0.f};

    for (int k0 = 0; k0 < OUTD; k0 += 32) {
        uint4 a0 = *(const uint4*)(Ag + k0);
        uint4 a1 = *(const uint4*)(Ag + k0 + 8);
        uint4 b0 = *(const uint4*)(Bg + k0);
        uint4 b1 = *(const uint4*)(Bg + k0 + 8);
        __syncthreads();
        *(uint4*)AsW0 = a0; *(uint4*)AsW1 = a1;
        *(uint4*)BsW0 = b0; *(uint4*)BsW1 = b1;
        __syncthreads();
        s16x8 af[4], bfv[4];
#pragma unroll
        for (int i = 0; i < 4; i++)
            af[i] = *(const s16x8*)&As[(quad * 128 + wm + i * 16 + fr) * 8];
#pragma unroll
        for (int j = 0; j < 4; j++)
            bfv[j] = *(const s16x8*)&Bs[(quad * 128 + wn + j * 16 + fr) * 8];
#pragma unroll
        for (int i = 0; i < 4; i++)
#pragma unroll
            for (int j = 0; j < 4; j++)
                acc[i][j] = __builtin_amdgcn_mfma_f32_16x16x32_bf16(af[i], bfv[j], acc[i][j], 0, 0, 0);
    }

    const int rb = quad * 4;
#pragma unroll
    for (int i = 0; i < 4; i++)
#pragma unroll
        for (int j = 0; j < 4; j++) {
            const int col = tile_n + wn + j * 16 + fr;
#pragma unroll
            for (int r = 0; r < 4; r++) {
                const int row = tile_m + wm + i * 16 + rb + r;
                C[(size_t)row * SN_PAD + col] = f2bf(acc[i][j][r] * 0.029462782549439484f);
            }
        }
}

// ---------------------------------------------------------------------------
// softmax over 5 blocks of 140 support cols; attn row stride 720
// ---------------------------------------------------------------------------
__global__ __launch_bounds__(256) void softmax_k(const bf16* __restrict__ sc,
                                                 bf16* __restrict__ attn) {
    int row = blockIdx.x, t = threadIdx.x, lane = t & 63, wave = t >> 6;
    __shared__ float redm[4], reds[4];
    for (int w = 0; w < 5; w++) {
        float v = (t < 140) ? bf2f(sc[(size_t)row * SN_PAD + w * 140 + t]) : -3.0e38f;
        float m = v;
        for (int o = 32; o > 0; o >>= 1) m = fmaxf(m, __shfl_xor(m, o));
        if (lane == 0) redm[wave] = m;
        __syncthreads();
        m = fmaxf(fmaxf(redm[0], redm[1]), fmaxf(redm[2], redm[3]));
        float e = (t < 140) ? __expf(v - m) : 0.f;
        float s = e;
        for (int o = 32; o > 0; o >>= 1) s += __shfl_xor(s, o);
        if (lane == 0) reds[wave] = s;
        __syncthreads();
        s = reds[0] + reds[1] + reds[2] + reds[3];
        if (t < 140) attn[(size_t)row * ATT_STRIDE + w * 140 + t] = f2bf(e / s);
        __syncthreads();
    }
}

// ---------------------------------------------------------------------------
// vsp[w][d][j] = vs[w*140+j][d] (j>=140 -> 0): B^T operand for proto GEMM
// ---------------------------------------------------------------------------
__global__ __launch_bounds__(256) void build_vspad(const bf16* __restrict__ vs,
                                                   bf16* __restrict__ vp) {
    int idx = blockIdx.x * 256 + threadIdx.x;
    if (idx >= 5 * OUTD * KP) return;
    int j = idx % KP;
    int rest = idx / KP;
    int dcol = rest % OUTD;
    int w = rest / OUTD;
    vp[idx] = (j < 140) ? vs[(size_t)(w * 140 + j) * OUTD + dcol] : f2bf(0.f);
}

// ---------------------------------------------------------------------------
// Gram reduce over a proto chunk. Block=(q_local, l-group of 4). Reads the 5
// class planes + vq elementwise, accumulates 21 stats -> gbuf via atomics.
// ---------------------------------------------------------------------------
__global__ __launch_bounds__(256) void gramred_k(const bf16* __restrict__ protoc,
                                                 const bf16* __restrict__ vs,
                                                 float* __restrict__ gbuf,
                                                 int row0, int q0) {
    const int ql = blockIdx.x;     // 0..49
    const int lg = blockIdx.y;     // 0..6
    const int t = threadIdx.x, lane = t & 63, wave = t >> 6;
    const size_t PZ = (size_t)CH_MPAD * OUTD;
    float g[15] = {0.f};
    float h[5] = {0.f, 0.f, 0.f, 0.f, 0.f};
    float e = 0.f;
    for (int idx = t; idx < 4 * OUTD; idx += 256) {
        int l = lg * 4 + idx / OUTD;
        int d = idx - (idx / OUTD) * OUTD;
        size_t ml = (size_t)(ql * LT + l) * OUTD + d;
        float pv[5];
#pragma unroll
        for (int w = 0; w < 5; w++) pv[w] = bf2f(protoc[w * PZ + ml]);
        float v = bf2f(vs[(size_t)(700 + row0 + ql * LT + l) * OUTD + d]);
        e += v * v;
        int c = 0;
#pragma unroll
        for (int a = 0; a < 5; a++) {
            h[a] += v * pv[a];
#pragma unroll
            for (int b = a; b < 5; b++) g[c++] += pv[a] * pv[b];
        }
    }
    float vals[21];
#pragma unroll
    for (int k = 0; k < 15; k++) vals[k] = g[k];
#pragma unroll
    for (int k = 0; k < 5; k++) vals[15 + k] = h[k];
    vals[20] = e;
#pragma unroll
    for (int k = 0; k < 21; k++)
        for (int o = 32; o > 0; o >>= 1) vals[k] += __shfl_xor(vals[k], o);
    __shared__ float red[4][21];
    if (lane == 0)
#pragma unroll
        for (int k = 0; k < 21; k++) red[wave][k] = vals[k];
    __syncthreads();
    if (t < 21) {
        float s = red[0][t] + red[1][t] + red[2][t] + red[3][t];
        atomicAdd(&gbuf[(q0 + ql) * 21 + t], s);
    }
}

// ---------------------------------------------------------------------------
// out (fp32): per q -> 25 sim + 5 ori
// ---------------------------------------------------------------------------
__global__ __launch_bounds__(64) void out_k(const float* __restrict__ gbuf,
                                            float* __restrict__ out) {
    int q = blockIdx.x;
    if (threadIdx.x != 0) return;
    const float* r = gbuf + q * 21;
    float G[5][5];
    int c = 0;
    for (int a = 0; a < 5; a++)
        for (int b = a; b < 5; b++) { G[a][b] = r[c]; G[b][a] = r[c]; c++; }
    float e = r[20];
    float nrm[5];
    for (int a = 0; a < 5; a++) nrm[a] = sqrtf(fmaxf(G[a][a], 0.f));
    for (int a = 0; a < 5; a++)
        for (int b = 0; b < 5; b++)
            out[(size_t)q * 25 + a * 5 + b] = G[a][b] / fmaxf(nrm[a] * nrm[b], 1e-8f);
    for (int w = 0; w < 5; w++)
        out[5000 + (size_t)q * 5 + w] = -(e - 2.f * r[15 + w] + G[w][w]) * (1.f / 28.f);
}

// ---------------------------------------------------------------------------
extern "C" void kernel_launch(void* const* d_in, const int* in_sizes, int n_in,
                              void* d_out, int out_size, void* d_ws, size_t ws_size,
                              hipStream_t stream) {
    const float* sup = (const float*)d_in[0];
    // d_in[1] = support_labels int32 — unused (sorted equal-shot)
    const float* qry = (const float*)d_in[2];
    const float* k_w = (const float*)d_in[3];
    const float* k_b = (const float*)d_in[4];
    const float* v_w = (const float*)d_in[5];
    const float* v_b = (const float*)d_in[6];
    const float* lng = (const float*)d_in[7];
    const float* lnb = (const float*)d_in[8];
    (void)in_sizes; (void)n_in; (void)out_size; (void)ws_size;

    // layout (bytes), peak 54,428,064 (<= verified ws_size >= 54,543,008):
    //   wbf    @0           9,437,184  (k_w/v_w bf16; dead after projections)
    //   pex    @9,437,184   7,372,800  (dead after projections)
    //   ks     @16,809,984 14,745,600  (dead after gemm_scores)
    //   vs     @31,555,584 14,745,600  (live to end)
    //   sc     @0           8,650,752  (alias wbf; dead after softmax)
    //   vsp    @16,809,984  1,843,200  (alias ks; built after gemm_scores)
    //   attn   @46,301,184  8,110,080  (5632 x 720)
    //   gbuf   @54,411,264     16,800
    //   protoc @0          16,220,160  (alias wbf+pex; after softmax)
    char* ws = (char*)d_ws;
    bf16* wbf    = (bf16*)(ws + 0);
    bf16* pex    = (bf16*)(ws + 9437184);
    bf16* ks     = (bf16*)(ws + 16809984);
    bf16* vs     = (bf16*)(ws + 31555584);
    bf16* sc     = (bf16*)(ws + 0);
    bf16* vsp    = (bf16*)(ws + 16809984);
    bf16* attn   = (bf16*)(ws + 46301184);
    float* gbuf  = (float*)(ws + 54411264);
    bf16* protoc = (bf16*)(ws + 0);

    pex_k<<<dim3(NPEX), dim3(256), 0, stream>>>(sup, qry, pex);

    wconv_k<<<dim3(4608), dim3(256), 0, stream>>>(
        (const float4*)k_w, (ushort4*)wbf);
    gemm_projx<<<dim3(50, 9), dim3(256), 0, stream>>>(
        (const unsigned short*)pex, (const unsigned short*)wbf, k_b, ks);

    wconv_k<<<dim3(4608), dim3(256), 0, stream>>>(
        (const float4*)v_w, (ushort4*)wbf);
    gemm_projx<<<dim3(50, 9), dim3(256), 0, stream>>>(
        (const unsigned short*)pex, (const unsigned short*)wbf, v_b, vs);

    ln_k<<<dim3(M_PAD), dim3(256), 0, stream>>>(ks, lng, lnb);

    gemm_scores<<<dim3(44, 6), dim3(256), 0, stream>>>(
        (const unsigned short*)(ks + (size_t)700 * OUTD),
        (const unsigned short*)ks, sc);

    build_vspad<<<dim3((5 * OUTD * KP + 255) / 256), dim3(256), 0, stream>>>(vs, vsp);

    softmax_k<<<dim3(SM), dim3(256), 0, stream>>>(sc, attn);

    hipMemsetAsync(gbuf, 0, 200 * 21 * sizeof(float), stream);

    // proto chunks: 4 x 50 queries; GEMM [1408x1152] per class then Gram-reduce
    for (int c = 0; c < 4; c++) {
        gemm_bt<<<dim3(11, 9, 5), dim3(256), 0, stream>>>(
            attn + (size_t)c * CH_ROWS * ATT_STRIDE, ATT_STRIDE, (size_t)140,
            vsp, KP, (size_t)OUTD * KP,
            1.0f, protoc, OUTD, (size_t)CH_MPAD * OUTD, KP);
        gramred_k<<<dim3(CH_Q, 7), dim3(256), 0, stream>>>(
            protoc, vs, gbuf, c * CH_ROWS, c * CH_Q);
    }

    out_k<<<dim3(NQ), dim3(64), 0, stream>>>(gbuf, (float*)d_out);
}

// Round 8
// 405.380 us; speedup vs baseline: 2.7422x; 1.1368x over previous
//
#include <hip/hip_runtime.h>
#include <hip/hip_bf16.h>
#include <math.h>

typedef __hip_bfloat16 bf16;
typedef short s16x8 __attribute__((ext_vector_type(8)));
typedef float f32x4 __attribute__((ext_vector_type(4)));

#define NQ 200
#define SEQ 8
#define DM 2048
#define OUTD 1152
#define LT 28
#define KDIM 4096
#define M_ALL 6300
#define M_PAD 6400
#define SM 5600
#define SN_PAD 768
#define ATT_STRIDE 720
#define NPEXB 1920      // 1800 distinct rows padded to 15 tiles of 128
#define N2 2304         // W viewed as [2304, 2048]
#define KP 160
#define CH_Q 50
#define CH_ROWS 1400
#define CH_MPAD 1408

__device__ __forceinline__ float bf2f(bf16 v) { return __bfloat162float(v); }
__device__ __forceinline__ bf16 f2bf(float v) { return __float2bfloat16(v); }
__device__ __forceinline__ float ubits2f(unsigned int u16) {
    unsigned int i = u16 << 16;
    float f; __builtin_memcpy(&f, &i, 4); return f;
}
__device__ __forceinline__ unsigned short f2bits(float f) {
    bf16 b = __float2bfloat16(f);
    unsigned short u; __builtin_memcpy(&u, &b, 2); return u;
}

__device__ const int TUP_A[LT] = {0,0,0,0,0,0,0,1,1,1,1,1,1,2,2,2,2,2,3,3,3,3,4,4,4,5,5,6};
__device__ const int TUP_B[LT] = {1,2,3,4,5,6,7,2,3,4,5,6,7,3,4,5,6,7,4,5,6,7,5,6,7,6,7,7};

// ---------------------------------------------------------------------------
// weight convert: fp32 -> bf16 (1152*4096 elements)
// ---------------------------------------------------------------------------
__global__ __launch_bounds__(256) void wconv_k(const float4* __restrict__ w,
                                               ushort4* __restrict__ o) {
    int i = blockIdx.x * 256 + threadIdx.x;
    float4 v = w[i];
    ushort4 r;
    r.x = f2bits(v.x); r.y = f2bits(v.y); r.z = f2bits(v.z); r.w = f2bits(v.w);
    o[i] = r;
}

// ---------------------------------------------------------------------------
// pexb[r][d] = fp32 src[n][s][d] + pe[s][d] -> bf16; rows >= 1800 zeroed
// ---------------------------------------------------------------------------
__global__ __launch_bounds__(256) void pex_k(const float* __restrict__ sup,
                                             const float* __restrict__ qry,
                                             bf16* __restrict__ pexb) {
    int r = blockIdx.x, t = threadIdx.x;
    bf16* orow = pexb + (size_t)r * DM;
    if (r >= 1800) {
        for (int d = t; d < DM; d += 256) orow[d] = f2bf(0.f);
        return;
    }
    int n, s;
    const float* src;
    if (r < 200) { n = r >> 3; s = r & 7; src = sup; }
    else { int rr = r - 200; n = rr >> 3; s = rr & 7; src = qry; }
    const float* row = src + ((size_t)n * SEQ + s) * DM;
    for (int d = t; d < DM; d += 256) {
        float dv = expf((float)(d & ~1) * (-9.210340371976184f / 2048.0f));
        float ang = (float)s * dv;
        float pe = (d & 1) ? cosf(ang) * 0.1f : sinf(ang) * 0.1f;
        orow[d] = f2bf(row[d] + pe);
    }
}

// ---------------------------------------------------------------------------
// Generic MFMA bf16 GEMM: C = scale*A*B^T (A[M,K], B[N,K] row-major, bf16 out)
// z shifts A/B/C by aZ/bZ/cZ elements. 128x128 tile, 4 waves, 4x4 16x16x32.
// ---------------------------------------------------------------------------
__global__ __launch_bounds__(256) void gemm_bt(
    const bf16* __restrict__ A, int lda, size_t aZ,
    const bf16* __restrict__ B, int ldb, size_t bZ,
    float scale, bf16* __restrict__ C, int ldc, size_t cZ, int K) {
    const unsigned short* Ag0 = (const unsigned short*)A + aZ * blockIdx.z;
    const unsigned short* Bg0 = (const unsigned short*)B + bZ * blockIdx.z;
    const size_t cbase = cZ * blockIdx.z;
    const int tile_m = blockIdx.x * 128, tile_n = blockIdx.y * 128;
    __shared__ unsigned short As[4 * 128 * 8];
    __shared__ unsigned short Bs[4 * 128 * 8];
    const int t = threadIdx.x, lane = t & 63, wave = t >> 6;
    const int wm = (wave & 1) * 64, wn = (wave >> 1) * 64;
    const int srow = t >> 1, sq0 = (t & 1) * 2;
    const unsigned short* Ag = Ag0 + (size_t)(tile_m + srow) * lda + (t & 1) * 16;
    const unsigned short* Bg = Bg0 + (size_t)(tile_n + srow) * ldb + (t & 1) * 16;
    unsigned short* AsW0 = &As[((sq0 + 0) * 128 + srow) * 8];
    unsigned short* AsW1 = &As[((sq0 + 1) * 128 + srow) * 8];
    unsigned short* BsW0 = &Bs[((sq0 + 0) * 128 + srow) * 8];
    unsigned short* BsW1 = &Bs[((sq0 + 1) * 128 + srow) * 8];
    const int fr = lane & 15, quad = lane >> 4;

    f32x4 acc[4][4];
#pragma unroll
    for (int i = 0; i < 4; i++)
#pragma unroll
        for (int j = 0; j < 4; j++) acc[i][j] = {0.f, 0.f, 0.f, 0.f};

    for (int k0 = 0; k0 < K; k0 += 32) {
        uint4 a0 = *(const uint4*)(Ag + k0);
        uint4 a1 = *(const uint4*)(Ag + k0 + 8);
        uint4 b0 = *(const uint4*)(Bg + k0);
        uint4 b1 = *(const uint4*)(Bg + k0 + 8);
        __syncthreads();
        *(uint4*)AsW0 = a0; *(uint4*)AsW1 = a1;
        *(uint4*)BsW0 = b0; *(uint4*)BsW1 = b1;
        __syncthreads();
        s16x8 af[4], bfv[4];
#pragma unroll
        for (int i = 0; i < 4; i++)
            af[i] = *(const s16x8*)&As[(quad * 128 + wm + i * 16 + fr) * 8];
#pragma unroll
        for (int j = 0; j < 4; j++)
            bfv[j] = *(const s16x8*)&Bs[(quad * 128 + wn + j * 16 + fr) * 8];
#pragma unroll
        for (int i = 0; i < 4; i++)
#pragma unroll
            for (int j = 0; j < 4; j++)
                acc[i][j] = __builtin_amdgcn_mfma_f32_16x16x32_bf16(af[i], bfv[j], acc[i][j], 0, 0, 0);
    }

    const int rb = quad * 4;
#pragma unroll
    for (int i = 0; i < 4; i++)
#pragma unroll
        for (int j = 0; j < 4; j++) {
            const int col = tile_n + wn + j * 16 + fr;
#pragma unroll
            for (int r = 0; r < 4; r++) {
                const int row = tile_m + wm + i * 16 + rb + r;
                C[cbase + (size_t)row * ldc + col] = f2bf(acc[i][j][r] * scale);
            }
        }
}

// ---------------------------------------------------------------------------
// combine: ks[m][n] = LN(Yk[ra][2n] + Yk[rb][2n+1] + kb[n]) and
//          vs[m][n] =    Yv[ra][2n] + Yv[rb][2n+1] + vb[n]
// One block per tuple-row m; rows >= M_ALL -> ks zeros (scores pad operand).
// ---------------------------------------------------------------------------
__global__ __launch_bounds__(256) void combine_k(
    const unsigned int* __restrict__ Yk, const unsigned int* __restrict__ Yv,
    const float* __restrict__ kb, const float* __restrict__ vb,
    const float* __restrict__ lng, const float* __restrict__ lnb,
    bf16* __restrict__ ks, bf16* __restrict__ vs) {
    const int m = blockIdx.x, t = threadIdx.x, lane = t & 63, wave = t >> 6;
    if (m >= M_ALL) {
        for (int c = t; c < OUTD; c += 256) ks[(size_t)m * OUTD + c] = f2bf(0.f);
        return;
    }
    int mm = m < 700 ? m : m - 700;
    int base = m < 700 ? 0 : 200;
    int nsamp = mm / LT, l = mm - nsamp * LT;
    const size_t ra = (size_t)(base + nsamp * 8 + TUP_A[l]) * (N2 / 2);
    const size_t rb = (size_t)(base + nsamp * 8 + TUP_B[l]) * (N2 / 2);
    const unsigned int* yka = Yk + ra;
    const unsigned int* ykb = Yk + rb;
    const unsigned int* yva = Yv + ra;
    const unsigned int* yvb = Yv + rb;

    float vals[5];
    int cnt = 0;
    float s = 0.f, s2 = 0.f;
    for (int n = t; n < OUTD; n += 256) {
        unsigned int ua = yka[n], ub = ykb[n];
        float vk = ubits2f(ua & 0xFFFFu) + ubits2f(ub >> 16) + kb[n];
        vals[cnt++] = vk;
        s += vk; s2 += vk * vk;
        unsigned int va = yva[n], vbu = yvb[n];
        vs[(size_t)m * OUTD + n] =
            f2bf(ubits2f(va & 0xFFFFu) + ubits2f(vbu >> 16) + vb[n]);
    }
    for (int o = 32; o > 0; o >>= 1) { s += __shfl_xor(s, o); s2 += __shfl_xor(s2, o); }
    __shared__ float r1[4], r2[4];
    if (lane == 0) { r1[wave] = s; r2[wave] = s2; }
    __syncthreads();
    s = r1[0] + r1[1] + r1[2] + r1[3];
    s2 = r2[0] + r2[1] + r2[2] + r2[3];
    float mu = s * (1.f / OUTD);
    float var = s2 * (1.f / OUTD) - mu * mu;
    float inv = rsqrtf(fmaxf(var, 0.f) + 1e-5f);
    cnt = 0;
    for (int n = t; n < OUTD; n += 256)
        ks[(size_t)m * OUTD + n] = f2bf((vals[cnt++] - mu) * inv * lng[n] + lnb[n]);
}

// ---------------------------------------------------------------------------
// softmax over 5 blocks of 140 support cols; attn row stride 720
// ---------------------------------------------------------------------------
__global__ __launch_bounds__(256) void softmax_k(const bf16* __restrict__ sc,
                                                 bf16* __restrict__ attn) {
    int row = blockIdx.x, t = threadIdx.x, lane = t & 63, wave = t >> 6;
    __shared__ float redm[4], reds[4];
    for (int w = 0; w < 5; w++) {
        float v = (t < 140) ? bf2f(sc[(size_t)row * SN_PAD + w * 140 + t]) : -3.0e38f;
        float m = v;
        for (int o = 32; o > 0; o >>= 1) m = fmaxf(m, __shfl_xor(m, o));
        if (lane == 0) redm[wave] = m;
        __syncthreads();
        m = fmaxf(fmaxf(redm[0], redm[1]), fmaxf(redm[2], redm[3]));
        float e = (t < 140) ? __expf(v - m) : 0.f;
        float s = e;
        for (int o = 32; o > 0; o >>= 1) s += __shfl_xor(s, o);
        if (lane == 0) reds[wave] = s;
        __syncthreads();
        s = reds[0] + reds[1] + reds[2] + reds[3];
        if (t < 140) attn[(size_t)row * ATT_STRIDE + w * 140 + t] = f2bf(e / s);
        __syncthreads();
    }
}

// ---------------------------------------------------------------------------
// vsp[w][d][j] = vs[w*140+j][d] (j>=140 -> 0): B^T operand for proto GEMM
// ---------------------------------------------------------------------------
__global__ __launch_bounds__(256) void build_vspad(const bf16* __restrict__ vs,
                                                   bf16* __restrict__ vp) {
    int idx = blockIdx.x * 256 + threadIdx.x;
    if (idx >= 5 * OUTD * KP) return;
    int j = idx % KP;
    int rest = idx / KP;
    int dcol = rest % OUTD;
    int w = rest / OUTD;
    vp[idx] = (j < 140) ? vs[(size_t)(w * 140 + j) * OUTD + dcol] : f2bf(0.f);
}

// ---------------------------------------------------------------------------
// Gram reduce over a proto chunk -> 21 sufficient stats per query
// ---------------------------------------------------------------------------
__global__ __launch_bounds__(256) void gramred_k(const bf16* __restrict__ protoc,
                                                 const bf16* __restrict__ vs,
                                                 float* __restrict__ gbuf,
                                                 int row0, int q0) {
    const int ql = blockIdx.x;
    const int lg = blockIdx.y;
    const int t = threadIdx.x, lane = t & 63, wave = t >> 6;
    const size_t PZ = (size_t)CH_MPAD * OUTD;
    float g[15] = {0.f};
    float h[5] = {0.f, 0.f, 0.f, 0.f, 0.f};
    float e = 0.f;
    for (int idx = t; idx < 4 * OUTD; idx += 256) {
        int l = lg * 4 + idx / OUTD;
        int d = idx - (idx / OUTD) * OUTD;
        size_t ml = (size_t)(ql * LT + l) * OUTD + d;
        float pv[5];
#pragma unroll
        for (int w = 0; w < 5; w++) pv[w] = bf2f(protoc[w * PZ + ml]);
        float v = bf2f(vs[(size_t)(700 + row0 + ql * LT + l) * OUTD + d]);
        e += v * v;
        int c = 0;
#pragma unroll
        for (int a = 0; a < 5; a++) {
            h[a] += v * pv[a];
#pragma unroll
            for (int b = a; b < 5; b++) g[c++] += pv[a] * pv[b];
        }
    }
    float vals[21];
#pragma unroll
    for (int k = 0; k < 15; k++) vals[k] = g[k];
#pragma unroll
    for (int k = 0; k < 5; k++) vals[15 + k] = h[k];
    vals[20] = e;
#pragma unroll
    for (int k = 0; k < 21; k++)
        for (int o = 32; o > 0; o >>= 1) vals[k] += __shfl_xor(vals[k], o);
    __shared__ float red[4][21];
    if (lane == 0)
#pragma unroll
        for (int k = 0; k < 21; k++) red[wave][k] = vals[k];
    __syncthreads();
    if (t < 21) {
        float s = red[0][t] + red[1][t] + red[2][t] + red[3][t];
        atomicAdd(&gbuf[(q0 + ql) * 21 + t], s);
    }
}

// ---------------------------------------------------------------------------
// out (fp32): per q -> 25 sim + 5 ori
// ---------------------------------------------------------------------------
__global__ __launch_bounds__(64) void out_k(const float* __restrict__ gbuf,
                                            float* __restrict__ out) {
    int q = blockIdx.x;
    if (threadIdx.x != 0) return;
    const float* r = gbuf + q * 21;
    float G[5][5];
    int c = 0;
    for (int a = 0; a < 5; a++)
        for (int b = a; b < 5; b++) { G[a][b] = r[c]; G[b][a] = r[c]; c++; }
    float e = r[20];
    float nrm[5];
    for (int a = 0; a < 5; a++) nrm[a] = sqrtf(fmaxf(G[a][a], 0.f));
    for (int a = 0; a < 5; a++)
        for (int b = 0; b < 5; b++)
            out[(size_t)q * 25 + a * 5 + b] = G[a][b] / fmaxf(nrm[a] * nrm[b], 1e-8f);
    for (int w = 0; w < 5; w++)
        out[5000 + (size_t)q * 5 + w] = -(e - 2.f * r[15 + w] + G[w][w]) * (1.f / 28.f);
}

// ---------------------------------------------------------------------------
extern "C" void kernel_launch(void* const* d_in, const int* in_sizes, int n_in,
                              void* d_out, int out_size, void* d_ws, size_t ws_size,
                              hipStream_t stream) {
    const float* sup = (const float*)d_in[0];
    // d_in[1] = support_labels int32 — unused (sorted equal-shot)
    const float* qry = (const float*)d_in[2];
    const float* k_w = (const float*)d_in[3];
    const float* k_b = (const float*)d_in[4];
    const float* v_w = (const float*)d_in[5];
    const float* v_b = (const float*)d_in[6];
    const float* lng = (const float*)d_in[7];
    const float* lnb = (const float*)d_in[8];
    (void)in_sizes; (void)n_in; (void)out_size; (void)ws_size;

    // layout (bytes), peak 49,758,624 (<= verified ws_size >= 54.5 MB):
    //   wbf    @0           9,437,184  dead after V proj GEMM
    //   pexb   @9,437,184   7,864,320  dead after V proj GEMM
    //   Yk     @17,301,504  8,847,360  dead after combine
    //   Yv     @26,148,864  8,847,360  dead after combine
    //   ks     @0          14,745,600  (over wbf+pexb) dead after scores
    //   vs     @34,996,224 14,745,600  live to end
    //   sc     @17,301,504  8,650,752  (over Yk) dead after softmax
    //   vsp    @14,745,600  1,843,200  (over pexb tail)
    //   attn   @0           8,110,080  (over ks after scores)
    //   protoc @17,301,504 16,220,160  (over sc/Yv)
    //   gbuf   @49,741,824     16,800
    char* ws = (char*)d_ws;
    bf16* wbf    = (bf16*)(ws + 0);
    bf16* pexb   = (bf16*)(ws + 9437184);
    bf16* Yk     = (bf16*)(ws + 17301504);
    bf16* Yv     = (bf16*)(ws + 26148864);
    bf16* ks     = (bf16*)(ws + 0);
    bf16* vs     = (bf16*)(ws + 34996224);
    bf16* sc     = (bf16*)(ws + 17301504);
    bf16* vsp    = (bf16*)(ws + 14745600);
    bf16* attn   = (bf16*)(ws + 0);
    bf16* protoc = (bf16*)(ws + 17301504);
    float* gbuf  = (float*)(ws + 49741824);

    pex_k<<<dim3(NPEXB), dim3(256), 0, stream>>>(sup, qry, pexb);

    // K projection on 1800 distinct rows: Yk[1920,2304] = pexb @ Wk_view^T
    wconv_k<<<dim3(4608), dim3(256), 0, stream>>>(
        (const float4*)k_w, (ushort4*)wbf);
    gemm_bt<<<dim3(15, 18), dim3(256), 0, stream>>>(
        pexb, DM, 0, wbf, DM, 0, 1.0f, Yk, N2, 0, DM);

    // V projection
    wconv_k<<<dim3(4608), dim3(256), 0, stream>>>(
        (const float4*)v_w, (ushort4*)wbf);
    gemm_bt<<<dim3(15, 18), dim3(256), 0, stream>>>(
        pexb, DM, 0, wbf, DM, 0, 1.0f, Yv, N2, 0, DM);

    // tuple combine + bias + LN(k-path)
    combine_k<<<dim3(M_PAD), dim3(256), 0, stream>>>(
        (const unsigned int*)Yk, (const unsigned int*)Yv,
        k_b, v_b, lng, lnb, ks, vs);

    // scores: ks_q[5632,1152] @ ks_s[768,1152]^T / sqrt(1152)
    gemm_bt<<<dim3(44, 6), dim3(256), 0, stream>>>(
        ks + (size_t)700 * OUTD, OUTD, 0, ks, OUTD, 0,
        0.029462782549439484f, sc, SN_PAD, 0, OUTD);

    build_vspad<<<dim3((5 * OUTD * KP + 255) / 256), dim3(256), 0, stream>>>(vs, vsp);

    softmax_k<<<dim3(SM), dim3(256), 0, stream>>>(sc, attn);

    hipMemsetAsync(gbuf, 0, 200 * 21 * sizeof(float), stream);

    // proto chunks: 4 x 50 queries; per-class GEMM then Gram reduce
    for (int c = 0; c < 4; c++) {
        gemm_bt<<<dim3(11, 9, 5), dim3(256), 0, stream>>>(
            attn + (size_t)c * CH_ROWS * ATT_STRIDE, ATT_STRIDE, (size_t)140,
            vsp, KP, (size_t)OUTD * KP,
            1.0f, protoc, OUTD, (size_t)CH_MPAD * OUTD, KP);
        gramred_k<<<dim3(CH_Q, 7), dim3(256), 0, stream>>>(
            protoc, vs, gbuf, c * CH_ROWS, c * CH_Q);
    }

    out_k<<<dim3(NQ), dim3(64), 0, stream>>>(gbuf, (float*)d_out);
}

// Round 9
// 364.299 us; speedup vs baseline: 3.0515x; 1.1128x over previous
//
#include <hip/hip_runtime.h>
#include <hip/hip_bf16.h>
#include <math.h>

typedef __hip_bfloat16 bf16;
typedef short s16x8 __attribute__((ext_vector_type(8)));
typedef float f32x4 __attribute__((ext_vector_type(4)));

#define NQ 200
#define SEQ 8
#define DM 2048
#define OUTD 1152
#define LT 28
#define M_ALL 6300
#define SM 5600
#define SN_PAD 768
#define ATT_STRIDE 720
#define N2 2304          // W viewed as [2304, 2048]
#define KP 160
#define CH_Q 50
#define CH_ROWS 1400
#define CH_MPAD 1408

__device__ __forceinline__ float bf2f(bf16 v) { return __bfloat162float(v); }
__device__ __forceinline__ bf16 f2bf(float v) { return __float2bfloat16(v); }
__device__ __forceinline__ float ubits2f(unsigned int u16) {
    unsigned int i = u16 << 16;
    float f; __builtin_memcpy(&f, &i, 4); return f;
}
__device__ __forceinline__ unsigned short f2bits(float f) {
    bf16 b = __float2bfloat16(f);
    unsigned short u; __builtin_memcpy(&u, &b, 2); return u;
}

__device__ const int TUP_A[LT] = {0,0,0,0,0,0,0,1,1,1,1,1,1,2,2,2,2,2,3,3,3,3,4,4,4,5,5,6};
__device__ const int TUP_B[LT] = {1,2,3,4,5,6,7,2,3,4,5,6,7,3,4,5,6,7,4,5,6,7,5,6,7,6,7,7};

// ---------------------------------------------------------------------------
// fused weight convert: [k_w | v_w] fp32 -> bf16 (2 x 1,179,648 float4)
// ---------------------------------------------------------------------------
__global__ __launch_bounds__(256) void wconv2_k(const float4* __restrict__ kw,
                                                const float4* __restrict__ vw,
                                                ushort4* __restrict__ o) {
    int i = blockIdx.x * 256 + threadIdx.x;     // 0 .. 2,359,295
    float4 v = (i < 1179648) ? kw[i] : vw[i - 1179648];
    ushort4 r;
    r.x = f2bits(v.x); r.y = f2bits(v.y); r.z = f2bits(v.z); r.w = f2bits(v.w);
    o[i] = r;
}

// ---------------------------------------------------------------------------
// pexb[r][d] = fp32 src[n][s][d] + pe[s][d] -> bf16 (1800 distinct rows)
// ---------------------------------------------------------------------------
__global__ __launch_bounds__(256) void pex_k(const float* __restrict__ sup,
                                             const float* __restrict__ qry,
                                             bf16* __restrict__ pexb) {
    int r = blockIdx.x, t = threadIdx.x;
    int n, s;
    const float* src;
    if (r < 200) { n = r >> 3; s = r & 7; src = sup; }
    else { int rr = r - 200; n = rr >> 3; s = rr & 7; src = qry; }
    const float* row = src + ((size_t)n * SEQ + s) * DM;
    bf16* orow = pexb + (size_t)r * DM;
    for (int d = t; d < DM; d += 256) {
        float dv = expf((float)(d & ~1) * (-9.210340371976184f / 2048.0f));
        float ang = (float)s * dv;
        float pe = (d & 1) ? cosf(ang) * 0.1f : sinf(ang) * 0.1f;
        orow[d] = f2bf(row[d] + pe);
    }
}

// ---------------------------------------------------------------------------
// Generic MFMA bf16 GEMM: C = scale*A*B^T; z shifts A/B/C by aZ/bZ/cZ elems.
// C rows >= mlim are not stored (M-pad garbage containment).
// ---------------------------------------------------------------------------
__global__ __launch_bounds__(256) void gemm_bt(
    const bf16* __restrict__ A, int lda, size_t aZ,
    const bf16* __restrict__ B, int ldb, size_t bZ,
    float scale, bf16* __restrict__ C, int ldc, size_t cZ, int K, int mlim) {
    const unsigned short* Ag0 = (const unsigned short*)A + aZ * blockIdx.z;
    const unsigned short* Bg0 = (const unsigned short*)B + bZ * blockIdx.z;
    const size_t cbase = cZ * blockIdx.z;
    const int tile_m = blockIdx.x * 128, tile_n = blockIdx.y * 128;
    __shared__ unsigned short As[4 * 128 * 8];
    __shared__ unsigned short Bs[4 * 128 * 8];
    const int t = threadIdx.x, lane = t & 63, wave = t >> 6;
    const int wm = (wave & 1) * 64, wn = (wave >> 1) * 64;
    const int srow = t >> 1, sq0 = (t & 1) * 2;
    const unsigned short* Ag = Ag0 + (size_t)(tile_m + srow) * lda + (t & 1) * 16;
    const unsigned short* Bg = Bg0 + (size_t)(tile_n + srow) * ldb + (t & 1) * 16;
    unsigned short* AsW0 = &As[((sq0 + 0) * 128 + srow) * 8];
    unsigned short* AsW1 = &As[((sq0 + 1) * 128 + srow) * 8];
    unsigned short* BsW0 = &Bs[((sq0 + 0) * 128 + srow) * 8];
    unsigned short* BsW1 = &Bs[((sq0 + 1) * 128 + srow) * 8];
    const int fr = lane & 15, quad = lane >> 4;

    f32x4 acc[4][4];
#pragma unroll
    for (int i = 0; i < 4; i++)
#pragma unroll
        for (int j = 0; j < 4; j++) acc[i][j] = {0.f, 0.f, 0.f, 0.f};

    for (int k0 = 0; k0 < K; k0 += 32) {
        uint4 a0 = *(const uint4*)(Ag + k0);
        uint4 a1 = *(const uint4*)(Ag + k0 + 8);
        uint4 b0 = *(const uint4*)(Bg + k0);
        uint4 b1 = *(const uint4*)(Bg + k0 + 8);
        __syncthreads();
        *(uint4*)AsW0 = a0; *(uint4*)AsW1 = a1;
        *(uint4*)BsW0 = b0; *(uint4*)BsW1 = b1;
        __syncthreads();
        s16x8 af[4], bfv[4];
#pragma unroll
        for (int i = 0; i < 4; i++)
            af[i] = *(const s16x8*)&As[(quad * 128 + wm + i * 16 + fr) * 8];
#pragma unroll
        for (int j = 0; j < 4; j++)
            bfv[j] = *(const s16x8*)&Bs[(quad * 128 + wn + j * 16 + fr) * 8];
#pragma unroll
        for (int i = 0; i < 4; i++)
#pragma unroll
            for (int j = 0; j < 4; j++)
                acc[i][j] = __builtin_amdgcn_mfma_f32_16x16x32_bf16(af[i], bfv[j], acc[i][j], 0, 0, 0);
    }

    const int rb = quad * 4;
#pragma unroll
    for (int i = 0; i < 4; i++)
#pragma unroll
        for (int j = 0; j < 4; j++) {
            const int col = tile_n + wn + j * 16 + fr;
#pragma unroll
            for (int r = 0; r < 4; r++) {
                const int row = tile_m + wm + i * 16 + rb + r;
                if (row < mlim)
                    C[cbase + (size_t)row * ldc + col] = f2bf(acc[i][j][r] * scale);
            }
        }
}

// ---------------------------------------------------------------------------
// combine_k: ks[m][n] = LN(Yk[ra][2n] + Yk[rb][2n+1] + kb[n])
// ---------------------------------------------------------------------------
__global__ __launch_bounds__(256) void combine_k(
    const unsigned int* __restrict__ Yk, const float* __restrict__ kb,
    const float* __restrict__ lng, const float* __restrict__ lnb,
    bf16* __restrict__ ks) {
    const int m = blockIdx.x, t = threadIdx.x, lane = t & 63, wave = t >> 6;
    int mm = m < 700 ? m : m - 700;
    int base = m < 700 ? 0 : 200;
    int nsamp = mm / LT, l = mm - nsamp * LT;
    const unsigned int* ya = Yk + (size_t)(base + nsamp * 8 + TUP_A[l]) * (N2 / 2);
    const unsigned int* yb = Yk + (size_t)(base + nsamp * 8 + TUP_B[l]) * (N2 / 2);
    float vals[5];
    int cnt = 0;
    float s = 0.f, s2 = 0.f;
    for (int n = t; n < OUTD; n += 256) {
        unsigned int ua = ya[n], ub = yb[n];
        float vk = ubits2f(ua & 0xFFFFu) + ubits2f(ub >> 16) + kb[n];
        vals[cnt++] = vk;
        s += vk; s2 += vk * vk;
    }
    for (int o = 32; o > 0; o >>= 1) { s += __shfl_xor(s, o); s2 += __shfl_xor(s2, o); }
    __shared__ float r1[4], r2[4];
    if (lane == 0) { r1[wave] = s; r2[wave] = s2; }
    __syncthreads();
    s = r1[0] + r1[1] + r1[2] + r1[3];
    s2 = r2[0] + r2[1] + r2[2] + r2[3];
    float mu = s * (1.f / OUTD);
    float var = s2 * (1.f / OUTD) - mu * mu;
    float inv = rsqrtf(fmaxf(var, 0.f) + 1e-5f);
    cnt = 0;
    for (int n = t; n < OUTD; n += 256)
        ks[(size_t)m * OUTD + n] = f2bf((vals[cnt++] - mu) * inv * lng[n] + lnb[n]);
}

// ---------------------------------------------------------------------------
// combine_v: vs[m][n] = Yv[ra][2n] + Yv[rb][2n+1] + vb[n]
// ---------------------------------------------------------------------------
__global__ __launch_bounds__(256) void combine_v(
    const unsigned int* __restrict__ Yv, const float* __restrict__ vb,
    bf16* __restrict__ vs) {
    const int m = blockIdx.x, t = threadIdx.x;
    int mm = m < 700 ? m : m - 700;
    int base = m < 700 ? 0 : 200;
    int nsamp = mm / LT, l = mm - nsamp * LT;
    const unsigned int* ya = Yv + (size_t)(base + nsamp * 8 + TUP_A[l]) * (N2 / 2);
    const unsigned int* yb = Yv + (size_t)(base + nsamp * 8 + TUP_B[l]) * (N2 / 2);
    for (int n = t; n < OUTD; n += 256) {
        unsigned int ua = ya[n], ub = yb[n];
        vs[(size_t)m * OUTD + n] =
            f2bf(ubits2f(ua & 0xFFFFu) + ubits2f(ub >> 16) + vb[n]);
    }
}

// ---------------------------------------------------------------------------
// softmax over 5 blocks of 140 support cols; zeroes pad cols 700..719
// ---------------------------------------------------------------------------
__global__ __launch_bounds__(256) void softmax_k(const bf16* __restrict__ sc,
                                                 bf16* __restrict__ attn) {
    int row = blockIdx.x, t = threadIdx.x, lane = t & 63, wave = t >> 6;
    __shared__ float redm[4], reds[4];
    for (int w = 0; w < 5; w++) {
        float v = (t < 140) ? bf2f(sc[(size_t)row * SN_PAD + w * 140 + t]) : -3.0e38f;
        float m = v;
        for (int o = 32; o > 0; o >>= 1) m = fmaxf(m, __shfl_xor(m, o));
        if (lane == 0) redm[wave] = m;
        __syncthreads();
        m = fmaxf(fmaxf(redm[0], redm[1]), fmaxf(redm[2], redm[3]));
        float e = (t < 140) ? __expf(v - m) : 0.f;
        float s = e;
        for (int o = 32; o > 0; o >>= 1) s += __shfl_xor(s, o);
        if (lane == 0) reds[wave] = s;
        __syncthreads();
        s = reds[0] + reds[1] + reds[2] + reds[3];
        if (t < 140) attn[(size_t)row * ATT_STRIDE + w * 140 + t] = f2bf(e / s);
        __syncthreads();
    }
    if (t < 20) attn[(size_t)row * ATT_STRIDE + 700 + t] = f2bf(0.f);  // K-pad
}

// ---------------------------------------------------------------------------
// vsp[w][d][j] = vs[w*140+j][d] (j>=140 -> 0); block 0 also zeroes gbuf
// ---------------------------------------------------------------------------
__global__ __launch_bounds__(256) void vspad_k(const bf16* __restrict__ vs,
                                               bf16* __restrict__ vp,
                                               float* __restrict__ gbuf) {
    int idx = blockIdx.x * 256 + threadIdx.x;
    if (blockIdx.x == 0)
        for (int i = threadIdx.x; i < NQ * 21; i += 256) gbuf[i] = 0.f;
    if (idx >= 5 * OUTD * KP) return;
    int j = idx % KP;
    int rest = idx / KP;
    int dcol = rest % OUTD;
    int w = rest / OUTD;
    vp[idx] = (j < 140) ? vs[(size_t)(w * 140 + j) * OUTD + dcol] : f2bf(0.f);
}

// ---------------------------------------------------------------------------
// Gram reduce over a proto chunk -> 21 sufficient stats per query
// ---------------------------------------------------------------------------
__global__ __launch_bounds__(256) void gramred_k(const bf16* __restrict__ protoc,
                                                 const bf16* __restrict__ vs,
                                                 float* __restrict__ gbuf,
                                                 int row0, int q0) {
    const int ql = blockIdx.x;
    const int lg = blockIdx.y;
    const int t = threadIdx.x, lane = t & 63, wave = t >> 6;
    const size_t PZ = (size_t)CH_MPAD * OUTD;
    float g[15] = {0.f};
    float h[5] = {0.f, 0.f, 0.f, 0.f, 0.f};
    float e = 0.f;
    for (int idx = t; idx < 4 * OUTD; idx += 256) {
        int l = lg * 4 + idx / OUTD;
        int d = idx - (idx / OUTD) * OUTD;
        size_t ml = (size_t)(ql * LT + l) * OUTD + d;
        float pv[5];
#pragma unroll
        for (int w = 0; w < 5; w++) pv[w] = bf2f(protoc[w * PZ + ml]);
        float v = bf2f(vs[(size_t)(700 + row0 + ql * LT + l) * OUTD + d]);
        e += v * v;
        int c = 0;
#pragma unroll
        for (int a = 0; a < 5; a++) {
            h[a] += v * pv[a];
#pragma unroll
            for (int b = a; b < 5; b++) g[c++] += pv[a] * pv[b];
        }
    }
    float vals[21];
#pragma unroll
    for (int k = 0; k < 15; k++) vals[k] = g[k];
#pragma unroll
    for (int k = 0; k < 5; k++) vals[15 + k] = h[k];
    vals[20] = e;
#pragma unroll
    for (int k = 0; k < 21; k++)
        for (int o = 32; o > 0; o >>= 1) vals[k] += __shfl_xor(vals[k], o);
    __shared__ float red[4][21];
    if (lane == 0)
#pragma unroll
        for (int k = 0; k < 21; k++) red[wave][k] = vals[k];
    __syncthreads();
    if (t < 21) {
        float s = red[0][t] + red[1][t] + red[2][t] + red[3][t];
        atomicAdd(&gbuf[(q0 + ql) * 21 + t], s);
    }
}

// ---------------------------------------------------------------------------
// out (fp32): per q -> 25 sim + 5 ori
// ---------------------------------------------------------------------------
__global__ __launch_bounds__(64) void out_k(const float* __restrict__ gbuf,
                                            float* __restrict__ out) {
    int q = blockIdx.x;
    if (threadIdx.x != 0) return;
    const float* r = gbuf + q * 21;
    float G[5][5];
    int c = 0;
    for (int a = 0; a < 5; a++)
        for (int b = a; b < 5; b++) { G[a][b] = r[c]; G[b][a] = r[c]; c++; }
    float e = r[20];
    float nrm[5];
    for (int a = 0; a < 5; a++) nrm[a] = sqrtf(fmaxf(G[a][a], 0.f));
    for (int a = 0; a < 5; a++)
        for (int b = 0; b < 5; b++)
            out[(size_t)q * 25 + a * 5 + b] = G[a][b] / fmaxf(nrm[a] * nrm[b], 1e-8f);
    for (int w = 0; w < 5; w++)
        out[5000 + (size_t)q * 5 + w] = -(e - 2.f * r[15 + w] + G[w][w]) * (1.f / 28.f);
}

// ---------------------------------------------------------------------------
extern "C" void kernel_launch(void* const* d_in, const int* in_sizes, int n_in,
                              void* d_out, int out_size, void* d_ws, size_t ws_size,
                              hipStream_t stream) {
    const float* sup = (const float*)d_in[0];
    // d_in[1] = support_labels int32 — unused (sorted equal-shot)
    const float* qry = (const float*)d_in[2];
    const float* k_w = (const float*)d_in[3];
    const float* k_b = (const float*)d_in[4];
    const float* v_w = (const float*)d_in[5];
    const float* v_b = (const float*)d_in[6];
    const float* lng = (const float*)d_in[7];
    const float* lnb = (const float*)d_in[8];
    (void)in_sizes; (void)n_in; (void)out_size; (void)ws_size;

    // layout (bytes), peak 49,356,192 (<= verified ws_size >= 54.5 MB):
    //   pexb   @0           7,864,320 (1920 rows; 1800 real)  dead after proj
    //   wbf    @7,864,320  18,874,368 (k|v bf16)              dead after proj
    //   Yk     @26,738,688  8,294,400 (1800x2304)             dead after comb_k
    //   Yv     @35,033,088  8,294,400                         dead after comb_v
    //   ks     @0          14,588,928 (6332 rows; 6300 real)  dead after scores
    //   vs     @16,220,160 14,515,200 (6300 rows)             live to end
    //   sc     @30,735,360  8,650,752 (over dead Yk/Yv head)  dead after softmax
    //   vsp    @39,386,112  1,843,200
    //   attn   @41,229,312  8,110,080 (5632 rows x 720)
    //   gbuf   @49,339,392     16,800
    //   protoc @0          16,220,160 (over dead ks, after scores)
    char* ws = (char*)d_ws;
    bf16* pexb   = (bf16*)(ws + 0);
    bf16* wbf    = (bf16*)(ws + 7864320);
    bf16* Yk     = (bf16*)(ws + 26738688);
    bf16* Yv     = (bf16*)(ws + 35033088);
    bf16* ks     = (bf16*)(ws + 0);
    bf16* vs     = (bf16*)(ws + 16220160);
    bf16* sc     = (bf16*)(ws + 30735360);
    bf16* vsp    = (bf16*)(ws + 39386112);
    bf16* attn   = (bf16*)(ws + 41229312);
    float* gbuf  = (float*)(ws + 49339392);
    bf16* protoc = (bf16*)(ws + 0);

    pex_k<<<dim3(1800), dim3(256), 0, stream>>>(sup, qry, pexb);
    wconv2_k<<<dim3(9216), dim3(256), 0, stream>>>(
        (const float4*)k_w, (const float4*)v_w, (ushort4*)wbf);

    // fused K+V projection: z in {k,v}; Y[1800,2304] = pexb @ W_view^T
    gemm_bt<<<dim3(15, 18, 2), dim3(256), 0, stream>>>(
        pexb, DM, 0, wbf, DM, (size_t)4718592,
        1.0f, Yk, N2, (size_t)4147200, DM, 1800);

    combine_k<<<dim3(M_ALL), dim3(256), 0, stream>>>(
        (const unsigned int*)Yk, k_b, lng, lnb, ks);
    combine_v<<<dim3(M_ALL), dim3(256), 0, stream>>>(
        (const unsigned int*)Yv, v_b, vs);

    // scores: ks_q[5632,1152] @ ks_s[768,1152]^T / sqrt(1152)
    gemm_bt<<<dim3(44, 6, 1), dim3(256), 0, stream>>>(
        ks + (size_t)700 * OUTD, OUTD, 0, ks, OUTD, 0,
        0.029462782549439484f, sc, SN_PAD, 0, OUTD, 5632);

    vspad_k<<<dim3((5 * OUTD * KP + 255) / 256), dim3(256), 0, stream>>>(
        vs, vsp, gbuf);
    softmax_k<<<dim3(SM), dim3(256), 0, stream>>>(sc, attn);

    // proto chunks: 4 x 50 queries; per-class GEMM then Gram reduce
    for (int c = 0; c < 4; c++) {
        gemm_bt<<<dim3(11, 9, 5), dim3(256), 0, stream>>>(
            attn + (size_t)c * CH_ROWS * ATT_STRIDE, ATT_STRIDE, (size_t)140,
            vsp, KP, (size_t)OUTD * KP,
            1.0f, protoc, OUTD, (size_t)CH_MPAD * OUTD, KP, CH_MPAD);
        gramred_k<<<dim3(CH_Q, 7), dim3(256), 0, stream>>>(
            protoc, vs, gbuf, c * CH_ROWS, c * CH_Q);
    }

    out_k<<<dim3(NQ), dim3(64), 0, stream>>>(gbuf, (float*)d_out);
}